// Round 16
// baseline (4354.507 us; speedup 1.0000x reference)
//
#include <hip/hip_runtime.h>
#include <hip/hip_bf16.h>
#include <math.h>

typedef unsigned short u16;
typedef unsigned int u32;
typedef __attribute__((ext_vector_type(8))) __bf16 bf16x8;
typedef __attribute__((ext_vector_type(4))) float f32x4;

#define LSTM_L 200
#define LSTM_B 2048
#define LSTM_HIN 64
#define LSTM_H 256
#define NCLUST 64
#define HALF_BETA 0.05f
#define LDS_BYTES 131072
#define ASSIGN_LDS 135424   // clT 64K + psum 64K + rowbuf 4K + pcnt 256
#define ASSIGN_BLOCKS 64

__device__ __forceinline__ void gload_lds16(const void* g, void* l) {
    __builtin_amdgcn_global_load_lds(
        (__attribute__((address_space(1))) const void*)g,
        (__attribute__((address_space(3))) void*)l, 16, 0, 0);
}

__device__ __forceinline__ float fast_sigmoid(float x) {
    return __builtin_amdgcn_rcpf(1.f + __expf(-x));
}
__device__ __forceinline__ float fast_tanh(float x) {
    return 2.f * __builtin_amdgcn_rcpf(1.f + __expf(-2.f * x)) - 1.f;
}
// Write-through store (agent scope, relaxed): data lands at the coherence
// point, no dirty L2 line left behind -> release fences find nothing to flush.
__device__ __forceinline__ void wt_store(u32* p, u32 v) {
    __hip_atomic_store(p, v, __ATOMIC_RELAXED, __HIP_MEMORY_SCOPE_AGENT);
}
__device__ __forceinline__ u32 cload(const u32* p) {
    return __hip_atomic_load(p, __ATOMIC_RELAXED, __HIP_MEMORY_SCOPE_AGENT);
}
// Bounded spin (tid==0 only): a protocol failure becomes a wrong answer,
// never a hung container (~55 ms cap).
__device__ __forceinline__ void spin_ge(u32* p, u32 target) {
    int guard = 0;
    while (cload(p) < target) {
        __builtin_amdgcn_s_sleep(8);
        if (++guard > (1 << 18)) break;
    }
}

// ---------------------------------------------------------------------------
// Weight pack into per-(nb,wn) fragment order (round-4 layout):
// i = ((((nb*4+wn)*NCH + ch)*2 + nf)*64 + lane)*8 + e
// j = (2*nf + (l15&1))*256 + nb*32 + wn*8 + (l15>>1); k = ch*32 + (lane>>4)*8 + e
// ---------------------------------------------------------------------------
template<int KIN>
__global__ __launch_bounds__(256) void pack_frag(
    const float* __restrict__ Wih, const float* __restrict__ Whh,
    u16* __restrict__ Wp)
{
    constexpr int NCH = (KIN + LSTM_H) / 32;
    const int total = 1024 * (KIN + LSTM_H);
    for (int i = blockIdx.x * 256 + threadIdx.x; i < total; i += gridDim.x * 256) {
        const int e = i & 7;
        int t = i >> 3;
        const int lane = t & 63; t >>= 6;
        const int nf = t & 1;    t >>= 1;
        const int ch = t % NCH;  t /= NCH;
        const int wn = t & 3;
        const int nb = t >> 2;
        const int l15 = lane & 15;
        const int j = (2 * nf + (l15 & 1)) * 256 + nb * 32 + wn * 8 + (l15 >> 1);
        const int k = ch * 32 + ((lane >> 4) << 3) + e;
        const float v = (k < KIN) ? Wih[(size_t)j * KIN + k]
                                  : Whh[(size_t)j * LSTM_H + (k - KIN)];
        Wp[i] = __builtin_bit_cast(u16, (__bf16)v);
    }
}

// ---------------------------------------------------------------------------
// Persistent flag-synced 2-layer LSTM. 256 blocks = 16 groups (mb) x
// {8 L0 + 8 L1 blocks}; 512 thr; weights in VGPRs (loaded once); c-state in
// registers for all 200 steps. Per slot: tid==0 spin (bounded) + acquire
// fence (cheap inv: nothing dirty anywhere) -> normal global_load_lds staging
// -> barrier-free MFMA -> wt_store epilogue -> barrier -> release fence
// (no-op wbl2) + counter increment. DAG identical to validated rounds 5/8.
// ---------------------------------------------------------------------------
__global__ __launch_bounds__(512, 1) void lstm_persist5(
    const float* __restrict__ X,
    const u16* __restrict__ Wp0, const u16* __restrict__ Wp1,
    const float* __restrict__ bih0, const float* __restrict__ bhh0,
    const float* __restrict__ bih1, const float* __restrict__ bhh1,
    u32* h0b0, u32* h0b1, u32* h1b0, u32* h1b1,
    float* __restrict__ latent, u32* cnt0, u32* cnt1)
{
    extern __shared__ char smem[];
    const int tid = threadIdx.x;
    const int lane = tid & 63;
    const int w = tid >> 6;
    const int wm = w >> 2;
    const int wn = w & 3;
    const int l15 = lane & 15;
    const int q = lane >> 4;
    const int gpar = l15 & 1;
    const int bi = (int)blockIdx.x;
    const int mb = bi & 15;
    const int layer = (bi >> 4) & 1;
    const int nb = bi >> 5;
    const int b0 = mb * 128;
    u32* c0p = cnt0 + mb * 32;
    u32* c1p = cnt1 + mb * 32;

    const int hcol = nb * 32 + wn * 8 + (l15 >> 1);
    const int rowA = wm * 64;
    const int qoff = q * 16;
    const int swzl = (l15 & 7) << 4;

    float cp[4][4];
#pragma unroll
    for (int mf = 0; mf < 4; ++mf)
#pragma unroll
        for (int r = 0; r < 4; ++r) cp[mf][r] = 0.f;

    u32* h0b[2] = {h0b0, h0b1};
    u32* h1b[2] = {h1b0, h1b1};

    if (layer == 0) {
        // ---------------- LAYER 0 ----------------
        bf16x8 Breg[10][2];
        {
            const u16* wp = Wp0 + (size_t)((nb * 4 + wn) * 10) * 1024 + lane * 8;
#pragma unroll
            for (int ch = 0; ch < 10; ++ch)
#pragma unroll
                for (int nf = 0; nf < 2; ++nf)
                    Breg[ch][nf] = *(const bf16x8*)(wp + (ch * 2 + nf) * 512);
        }
        const float bA = bih0[gpar * 256 + hcol] + bhh0[gpar * 256 + hcol];
        const float bB = bih0[(2 + gpar) * 256 + hcol] + bhh0[(2 + gpar) * 256 + hcol];

        for (int s = 0; s < LSTM_L; ++s) {
            // X prefetch (normal loads; read-only data) before the wait
            float4 xv[2][2];
#pragma unroll
            for (int p = 0; p < 2; ++p) {
                const int slot = p * 512 + tid;
                const int row = slot >> 3;
                const int so = (slot & 7) * 16;
                const int koff = so ^ ((row & 7) << 4);
                const float* sp = X + (size_t)s * LSTM_B * LSTM_HIN
                                  + (size_t)(b0 + row) * 64 + (koff >> 1);
                xv[p][0] = *(const float4*)sp;
                xv[p][1] = *(const float4*)(sp + 4);
            }
            if (tid == 0) {
                if (s >= 1) spin_ge(c0p, 8u * s);
                if (s >= 2) spin_ge(c1p, 8u * (s - 1));
                if (s >= 1) __builtin_amdgcn_fence(__ATOMIC_ACQUIRE, "agent");
            }
            __syncthreads();

            // stage h0^{s-1} -> LDS [128][512B] swizzled (normal loads,
            // fresh-from-L3 after the acquire invalidate)
            const u32* hself = h0b[(s + 1) & 1];
#pragma unroll
            for (int i = 0; i < 8; ++i) {
                const int slot = i * 512 + tid;
                const int row = slot >> 5;
                const int so = (slot & 31) * 16;
                const int koff = so ^ ((row & 7) << 4);
                gload_lds16((const char*)hself + (size_t)(b0 + row) * 512 + koff,
                            smem + slot * 16);
            }
            // X region [128][128B] at 65536 from prefetched regs
#pragma unroll
            for (int p = 0; p < 2; ++p) {
                const int slot = p * 512 + tid;
                bf16x8 pk;
                pk[0] = (__bf16)xv[p][0].x; pk[1] = (__bf16)xv[p][0].y;
                pk[2] = (__bf16)xv[p][0].z; pk[3] = (__bf16)xv[p][0].w;
                pk[4] = (__bf16)xv[p][1].x; pk[5] = (__bf16)xv[p][1].y;
                pk[6] = (__bf16)xv[p][1].z; pk[7] = (__bf16)xv[p][1].w;
                *(bf16x8*)(smem + 65536 + slot * 16) = pk;
            }
            __syncthreads();

            f32x4 acc[4][2];
#pragma unroll
            for (int mf = 0; mf < 4; ++mf)
#pragma unroll
                for (int nf = 0; nf < 2; ++nf) acc[mf][nf] = f32x4{0.f,0.f,0.f,0.f};
#pragma unroll
            for (int ch = 0; ch < 10; ++ch) {
                bf16x8 af[4];
#pragma unroll
                for (int mf = 0; mf < 4; ++mf) {
                    const int row = rowA + mf * 16 + l15;
                    const char* ap = (ch < 2)
                        ? smem + 65536 + row * 128 + ((ch * 64 + qoff) ^ swzl)
                        : smem + row * 512 + (((ch - 2) * 64 + qoff) ^ swzl);
                    af[mf] = *(const bf16x8*)ap;
                }
#pragma unroll
                for (int mf = 0; mf < 4; ++mf)
#pragma unroll
                    for (int nf = 0; nf < 2; ++nf)
                        acc[mf][nf] = __builtin_amdgcn_mfma_f32_16x16x32_bf16(
                            af[mf], Breg[ch][nf], acc[mf][nf], 0, 0, 0);
            }

            // epilogue: c in regs; h via packed u32 wt_store
            u32* hdst = h0b[s & 1];
#pragma unroll
            for (int mf = 0; mf < 4; ++mf) {
#pragma unroll
                for (int r = 0; r < 4; ++r) {
                    const float a0 = acc[mf][0][r] + bA;
                    const float a1 = acc[mf][1][r] + bB;
                    const float p0 = __shfl_xor(a0, 1);
                    const float p1 = __shfl_xor(a1, 1);
                    const float gi = gpar ? p0 : a0;
                    const float gf = gpar ? a0 : p0;
                    const float gg = gpar ? p1 : a1;
                    const float go = gpar ? a1 : p1;
                    const float cn = fast_sigmoid(gf) * cp[mf][r]
                                   + fast_sigmoid(gi) * fast_tanh(gg);
                    cp[mf][r] = cn;
                    const float hv = fast_sigmoid(go) * fast_tanh(cn);
                    const int rowo = b0 + rowA + mf * 16 + q * 4 + r;
                    const u16 hb = __builtin_bit_cast(u16, (__bf16)hv);
                    const int pr = __shfl_xor((int)(u32)hb, 2);
                    const u32 pk = ((u32)hb & 0xffffu) | (((u32)pr) << 16);
                    if ((l15 & 3) == 0)
                        wt_store(hdst + (size_t)rowo * 128 + (hcol >> 1), pk);
                }
            }
            __syncthreads();   // all waves' stores drained (vmcnt at barrier)
            if (tid == 0) {
                __builtin_amdgcn_fence(__ATOMIC_RELEASE, "agent"); // no dirty data
                __hip_atomic_fetch_add(c0p, 1, __ATOMIC_RELAXED,
                                       __HIP_MEMORY_SCOPE_AGENT);
            }
        }
    } else {
        // ---------------- LAYER 1 ----------------
        bf16x8 Breg[16][2];
        {
            const u16* wp = Wp1 + (size_t)((nb * 4 + wn) * 16) * 1024 + lane * 8;
#pragma unroll
            for (int ch = 0; ch < 16; ++ch)
#pragma unroll
                for (int nf = 0; nf < 2; ++nf)
                    Breg[ch][nf] = *(const bf16x8*)(wp + (ch * 2 + nf) * 512);
        }
        const float bA = bih1[gpar * 256 + hcol] + bhh1[gpar * 256 + hcol];
        const float bB = bih1[(2 + gpar) * 256 + hcol] + bhh1[(2 + gpar) * 256 + hcol];

        for (int s = 1; s <= LSTM_L; ++s) {
            if (tid == 0) {
                spin_ge(c0p, 8u * s);
                if (s >= 2) spin_ge(c1p, 8u * (s - 1));
                __builtin_amdgcn_fence(__ATOMIC_ACQUIRE, "agent");
            }
            __syncthreads();

            // stage [128][1024B]: bytes 0..511 = h0^{s-1}, 512..1023 = h1^{s-2}
            const u32* hbelow = h0b[(s + 1) & 1];
            const u32* hself  = h1b[s & 1];
#pragma unroll
            for (int i = 0; i < 16; ++i) {
                const int slot = i * 512 + tid;
                const int row = slot >> 6;
                const int so = (slot & 63) * 16;
                const int koff = so ^ ((row & 7) << 4);
                const char* src = (koff < 512)
                    ? (const char*)hbelow + (size_t)(b0 + row) * 512 + koff
                    : (const char*)hself + (size_t)(b0 + row) * 512 + (koff - 512);
                gload_lds16(src, smem + slot * 16);
            }
            __syncthreads();

            f32x4 acc[4][2];
#pragma unroll
            for (int mf = 0; mf < 4; ++mf)
#pragma unroll
                for (int nf = 0; nf < 2; ++nf) acc[mf][nf] = f32x4{0.f,0.f,0.f,0.f};
#pragma unroll
            for (int ch = 0; ch < 16; ++ch) {
                bf16x8 af[4];
#pragma unroll
                for (int mf = 0; mf < 4; ++mf) {
                    const int row = rowA + mf * 16 + l15;
                    af[mf] = *(const bf16x8*)(smem + row * 1024 +
                                              ((ch * 64 + qoff) ^ swzl));
                }
#pragma unroll
                for (int mf = 0; mf < 4; ++mf)
#pragma unroll
                    for (int nf = 0; nf < 2; ++nf)
                        acc[mf][nf] = __builtin_amdgcn_mfma_f32_16x16x32_bf16(
                            af[mf], Breg[ch][nf], acc[mf][nf], 0, 0, 0);
            }

            u32* hdst = h1b[(s + 1) & 1];
            const bool fin = (s == LSTM_L);
#pragma unroll
            for (int mf = 0; mf < 4; ++mf) {
#pragma unroll
                for (int r = 0; r < 4; ++r) {
                    const float a0 = acc[mf][0][r] + bA;
                    const float a1 = acc[mf][1][r] + bB;
                    const float p0 = __shfl_xor(a0, 1);
                    const float p1 = __shfl_xor(a1, 1);
                    const float gi = gpar ? p0 : a0;
                    const float gf = gpar ? a0 : p0;
                    const float gg = gpar ? p1 : a1;
                    const float go = gpar ? a1 : p1;
                    const float cn = fast_sigmoid(gf) * cp[mf][r]
                                   + fast_sigmoid(gi) * fast_tanh(gg);
                    cp[mf][r] = cn;
                    const float hv = fast_sigmoid(go) * fast_tanh(cn);
                    const int rowo = b0 + rowA + mf * 16 + q * 4 + r;
                    if (fin) {
                        if (!gpar)
                            wt_store((u32*)&latent[(size_t)rowo * 256 + hcol],
                                     __builtin_bit_cast(u32, hv));
                    } else {
                        const u16 hb = __builtin_bit_cast(u16, (__bf16)hv);
                        const int pr = __shfl_xor((int)(u32)hb, 2);
                        const u32 pk = ((u32)hb & 0xffffu) | (((u32)pr) << 16);
                        if ((l15 & 3) == 0)
                            wt_store(hdst + (size_t)rowo * 128 + (hcol >> 1), pk);
                    }
                }
            }
            __syncthreads();
            if (tid == 0 && s < LSTM_L) {
                __builtin_amdgcn_fence(__ATOMIC_RELEASE, "agent");
                __hip_atomic_fetch_add(c1p, 1, __ATOMIC_RELAXED,
                                       __HIP_MEMORY_SCOPE_AGENT);
            }
        }
    }
}

// ---------------------------------------------------------------------------
// K-means tail (round-15 proven): 64 blocks x 256 thr, 32 rows = 4 waves x 8.
// ---------------------------------------------------------------------------
__global__ __launch_bounds__(256, 1) void assign_fused(
    const float* __restrict__ lat, const float* __restrict__ clusters,
    int* __restrict__ ids, float* __restrict__ partial, int* __restrict__ pcount)
{
    extern __shared__ char sm[];
    float* clT    = (float*)sm;                 // [j][k], 64 KB
    float* psum   = (float*)(sm + 65536);       // [k][h], 64 KB
    float* rowbuf = (float*)(sm + 131072);      // [wave][256], 4 KB
    int*   pcnt   = (int*)(sm + 135168);        // [64]

    const int tid = threadIdx.x;
    const int k = tid & 63;
    const int w = tid >> 6;

    for (int i = tid; i < 16384; i += 256) {
        const int kk = i >> 8, j = i & 255;
        clT[j * 64 + kk] = clusters[(size_t)kk * 256 + j];
        psum[i] = 0.f;
    }
    if (tid < 64) pcnt[tid] = 0;
    __syncthreads();

    float* rb = rowbuf + w * 256;
    const int rbase = (int)blockIdx.x * 32 + w * 8;
    for (int rr = 0; rr < 8; ++rr) {
        const int row = rbase + rr;
#pragma unroll
        for (int p = 0; p < 4; ++p)
            rb[p * 64 + k] = lat[(size_t)row * 256 + p * 64 + k];
        float d0 = 0.f, d1 = 0.f, d2 = 0.f, d3 = 0.f;
#pragma unroll 4
        for (int j = 0; j < 256; j += 4) {
            const float t0 = rb[j + 0] - clT[(j + 0) * 64 + k];
            const float t1 = rb[j + 1] - clT[(j + 1) * 64 + k];
            const float t2 = rb[j + 2] - clT[(j + 2) * 64 + k];
            const float t3 = rb[j + 3] - clT[(j + 3) * 64 + k];
            d0 += t0 * t0; d1 += t1 * t1; d2 += t2 * t2; d3 += t3 * t3;
        }
        float d = (d0 + d1) + (d2 + d3);
        int idx = k;
        for (int off = 32; off > 0; off >>= 1) {
            const float od = __shfl_down(d, off, 64);
            const int   oi = __shfl_down(idx, off, 64);
            if (od < d || (od == d && oi < idx)) { d = od; idx = oi; }
        }
        const int best = __shfl(idx, 0, 64);
        if (k == 0) { ids[row] = best; atomicAdd(&pcnt[best], 1); }
#pragma unroll
        for (int p = 0; p < 4; ++p)
            atomicAdd(&psum[best * 256 + p * 64 + k], rb[p * 64 + k]);
    }
    __syncthreads();
    for (int i = tid; i < 16384; i += 256)
        partial[(size_t)blockIdx.x * 16384 + i] = psum[i];
    if (tid < 64) pcount[(size_t)blockIdx.x * 64 + tid] = pcnt[tid];
}

__global__ __launch_bounds__(256) void centroid_final2(
    const float* __restrict__ partial, const int* __restrict__ pcount,
    const float* __restrict__ clusters, float* __restrict__ upd)
{
    const int k = blockIdx.x;
    const int h = threadIdx.x;
    float s = 0.f;
    int c = 0;
    for (int b = 0; b < ASSIGN_BLOCKS; ++b) {
        s += partial[(size_t)b * 16384 + k * 256 + h];
        c += pcount[(size_t)b * 64 + k];
    }
    upd[(size_t)k * LSTM_H + h] = (c > 0)
        ? s / (float)c
        : clusters[(size_t)k * LSTM_H + h];
}

__global__ __launch_bounds__(256) void loss_kernel(
    const float* __restrict__ lat, const int* __restrict__ ids,
    const float* __restrict__ upd, float* __restrict__ out_loss)
{
    float p = 0.f;
    const int total = LSTM_B * LSTM_H;
    for (int idx = blockIdx.x * blockDim.x + threadIdx.x; idx < total;
         idx += gridDim.x * blockDim.x) {
        const int b = idx >> 8;
        const float d = lat[idx] - upd[(size_t)ids[b] * LSTM_H + (idx & 255)];
        p += d * d;
    }
    for (int off = 32; off > 0; off >>= 1) p += __shfl_down(p, off, 64);
    __shared__ float wsum[4];
    const int lane = threadIdx.x & 63, wid = threadIdx.x >> 6;
    if (lane == 0) wsum[wid] = p;
    __syncthreads();
    if (threadIdx.x == 0)
        atomicAdd(out_loss, HALF_BETA * (wsum[0] + wsum[1] + wsum[2] + wsum[3]));
}

// ---------------------------------------------------------------------------
extern "C" void kernel_launch(void* const* d_in, const int* in_sizes, int n_in,
                              void* d_out, int out_size, void* d_ws, size_t ws_size,
                              hipStream_t stream)
{
    const float* X     = (const float*)d_in[0];
    const float* Wih0  = (const float*)d_in[1];
    const float* Whh0  = (const float*)d_in[2];
    const float* bih0  = (const float*)d_in[3];
    const float* bhh0  = (const float*)d_in[4];
    const float* Wih1  = (const float*)d_in[5];
    const float* Whh1  = (const float*)d_in[6];
    const float* bih1  = (const float*)d_in[7];
    const float* bhh1  = (const float*)d_in[8];
    const float* clust = (const float*)d_in[9];

    float* out = (float*)d_out;
    char* base = (char*)d_ws;
    const size_t MB = 1u << 20;
    const size_t KB = 1024;

    u16* Wp0      = (u16*)(base + 0 * MB);              // 640 KB
    u16* Wp1      = (u16*)(base + 1 * MB);              // 1 MB
    u32* h0b0     = (u32*)(base + 2 * MB);              // 1 MB each
    u32* h0b1     = (u32*)(base + 3 * MB);
    u32* h1b0     = (u32*)(base + 4 * MB);
    u32* h1b1     = (u32*)(base + 5 * MB);
    float* partial= (float*)(base + 6 * MB);            // 4 MB (64 x 64 KB)
    float* upd    = (float*)(base + 10 * MB);           // 64 KB
    int* pcount   = (int*)(base + 10 * MB + 64 * KB);   // 16 KB
    int* ids      = (int*)(base + 10 * MB + 80 * KB);   // 8 KB
    u32* cnt0     = (u32*)(base + 10 * MB + 88 * KB);   // 2 KB
    u32* cnt1     = (u32*)(base + 10 * MB + 90 * KB);   // 2 KB

    const size_t BH = (size_t)LSTM_B * LSTM_H;

    hipMemsetAsync(h0b1, 0, MB, stream);                // h0^{-1}
    hipMemsetAsync(h1b1, 0, MB, stream);                // h1^{-1}
    hipMemsetAsync(base + 10 * MB + 88 * KB, 0, 4 * KB, stream);  // cnt0+cnt1
    hipMemsetAsync(out + BH, 0, sizeof(float), stream);

    pack_frag<LSTM_HIN><<<320, 256, 0, stream>>>(Wih0, Whh0, Wp0);
    pack_frag<LSTM_H>  <<<512, 256, 0, stream>>>(Wih1, Whh1, Wp1);

    hipFuncSetAttribute((const void*)lstm_persist5,
                        hipFuncAttributeMaxDynamicSharedMemorySize, LDS_BYTES);
    hipFuncSetAttribute((const void*)assign_fused,
                        hipFuncAttributeMaxDynamicSharedMemorySize, ASSIGN_LDS);

    float* lat = out;
    void* args[] = {
        (void*)&X, (void*)&Wp0, (void*)&Wp1,
        (void*)&bih0, (void*)&bhh0, (void*)&bih1, (void*)&bhh1,
        (void*)&h0b0, (void*)&h0b1, (void*)&h1b0, (void*)&h1b1,
        (void*)&lat, (void*)&cnt0, (void*)&cnt1
    };
    hipLaunchCooperativeKernel((void*)lstm_persist5, dim3(256), dim3(512),
                               args, LDS_BYTES, stream);

    assign_fused<<<ASSIGN_BLOCKS, 256, ASSIGN_LDS, stream>>>(
        out, clust, ids, partial, pcount);
    centroid_final2<<<NCLUST, 256, 0, stream>>>(partial, pcount, clust, upd);
    loss_kernel<<<256, 256, 0, stream>>>(out, ids, upd, out + BH);
}

// Round 17
// 2456.110 us; speedup vs baseline: 1.7729x; 1.7729x over previous
//
#include <hip/hip_runtime.h>
#include <hip/hip_bf16.h>
#include <math.h>

typedef unsigned short u16;
typedef unsigned int u32;
typedef __attribute__((ext_vector_type(8))) __bf16 bf16x8;
typedef __attribute__((ext_vector_type(4))) float f32x4;

#define LSTM_L 200
#define LSTM_B 2048
#define LSTM_HIN 64
#define LSTM_H 256
#define NCLUST 64
#define HALF_BETA 0.05f
#define LDS_BYTES 65536     // 64-row tiles: L1 64KB, L0 40KB -> 2 blocks/CU
#define ASSIGN_LDS 135424   // clT 64K + psum 64K + rowbuf 4K + pcnt 256
#define ASSIGN_BLOCKS 64

__device__ __forceinline__ void gload_lds16(const void* g, void* l) {
    __builtin_amdgcn_global_load_lds(
        (__attribute__((address_space(1))) const void*)g,
        (__attribute__((address_space(3))) void*)l, 16, 0, 0);
}

__device__ __forceinline__ float fast_sigmoid(float x) {
    return __builtin_amdgcn_rcpf(1.f + __expf(-x));
}
__device__ __forceinline__ float fast_tanh(float x) {
    return 2.f * __builtin_amdgcn_rcpf(1.f + __expf(-2.f * x)) - 1.f;
}
// Write-through store (measured neutral-to-positive in the multi-launch
// structure, rounds 10 vs 13); h/c/latent producers use it.
__device__ __forceinline__ void wt_store(u32* p, u32 v) {
    __hip_atomic_store(p, v, __ATOMIC_RELAXED, __HIP_MEMORY_SCOPE_AGENT);
}

// ---------------------------------------------------------------------------
// Weight pack into per-(nb,wn) fragment order (round-4 layout, unchanged):
// i = ((((nb*4+wn)*NCH + ch)*2 + nf)*64 + lane)*8 + e
// j = (2*nf + (l15&1))*256 + nb*32 + wn*8 + (l15>>1); k = ch*32 + (lane>>4)*8 + e
// ---------------------------------------------------------------------------
template<int KIN>
__global__ __launch_bounds__(256) void pack_frag(
    const float* __restrict__ Wih, const float* __restrict__ Whh,
    u16* __restrict__ Wp)
{
    constexpr int NCH = (KIN + LSTM_H) / 32;
    const int total = 1024 * (KIN + LSTM_H);
    for (int i = blockIdx.x * 256 + threadIdx.x; i < total; i += gridDim.x * 256) {
        const int e = i & 7;
        int t = i >> 3;
        const int lane = t & 63; t >>= 6;
        const int nf = t & 1;    t >>= 1;
        const int ch = t % NCH;  t /= NCH;
        const int wn = t & 3;
        const int nb = t >> 2;
        const int l15 = lane & 15;
        const int j = (2 * nf + (l15 & 1)) * 256 + nb * 32 + wn * 8 + (l15 >> 1);
        const int k = ch * 32 + ((lane >> 4) << 3) + e;
        const float v = (k < KIN) ? Wih[(size_t)j * KIN + k]
                                  : Whh[(size_t)j * LSTM_H + (k - KIN)];
        Wp[i] = __builtin_bit_cast(u16, (__bf16)v);
    }
}

// ---------------------------------------------------------------------------
// One layer step, 64-row tile. Block = 64 rows x 128 gatecols; 4 waves
// (wn = wave id); wave = 64 rows x 32 cols (4 m-frags x 2 n-frags of
// 16x16x32 bf16 MFMA). B in VGPRs; A staged to LDS (XOR-swizzled source,
// linear dest); barrier-free K loop; wt_store epilogue. 2 blocks/CU ->
// one block's Breg-reload/staging overlaps the other's MFMA phase.
// ---------------------------------------------------------------------------
template<int KIN>
__device__ __forceinline__ void run_layer64(
    const float* __restrict__ xf32,     // L0: X slice (f32), else nullptr
    const u16* __restrict__ hbelow,     // L1: h0 current; L0: unused
    const u16* __restrict__ hself,      // recurrent hidden (bf16)
    const u16* __restrict__ Wp,
    const float* __restrict__ bih, const float* __restrict__ bhh,
    u16* __restrict__ hout, float* __restrict__ latout,
    float* __restrict__ cst,
    int blk, char* smem, int tid)
{
    constexpr int NCH = (KIN + LSTM_H) / 32;
    constexpr bool IS_L0 = (KIN == 64);
    const int lane = tid & 63;
    const int wn = tid >> 6;          // wave 0..3 = n-slice
    const int l15 = lane & 15;
    const int q = lane >> 4;          // 0..3
    const int mb = blk >> 3;          // 0..31
    const int nb = blk & 7;
    const int b0 = mb * 64;

    // ---- B into registers (frag-packed, contiguous 16B loads) ----
    bf16x8 Breg[NCH][2];
    {
        const u16* wp = Wp + (size_t)((nb * 4 + wn) * NCH) * 1024 + lane * 8;
#pragma unroll
        for (int ch = 0; ch < NCH; ++ch)
#pragma unroll
            for (int nf = 0; nf < 2; ++nf)
                Breg[ch][nf] = *(const bf16x8*)(wp + (ch * 2 + nf) * 512);
    }

    // ---- c-state preload ----
    const int hcol = nb * 32 + wn * 8 + (l15 >> 1);
    float cp[4][4];
#pragma unroll
    for (int mf = 0; mf < 4; ++mf)
#pragma unroll
        for (int r = 0; r < 4; ++r)
            cp[mf][r] = cst[(size_t)(b0 + mf * 16 + q * 4 + r) * 256 + hcol];

    // ---- bias ----
    const int gpar = l15 & 1;
    const float b0a = bih[gpar * 256 + hcol] + bhh[gpar * 256 + hcol];
    const float b1a = bih[(2 + gpar) * 256 + hcol] + bhh[(2 + gpar) * 256 + hcol];

    // ---- stage A into LDS (swizzled source, linear dest) ----
    if (IS_L0) {
        // H region: [64 rows][512 B] at 0 (32KB), via global_load_lds
#pragma unroll
        for (int i = 0; i < 8; ++i) {
            const int slot = i * 256 + tid;        // 2048 slots
            const int row = slot >> 5;
            const int so = (slot & 31) * 16;
            const int koff = so ^ ((row & 7) << 4);
            gload_lds16((const char*)hself + (size_t)(b0 + row) * 512 + koff,
                        smem + slot * 16);
        }
        // X region: [64 rows][128 B] at 32768 (8KB), reg-convert f32->bf16
#pragma unroll
        for (int p = 0; p < 2; ++p) {
            const int slot = p * 256 + tid;        // 512 slots
            const int row = slot >> 3;
            const int so = (slot & 7) * 16;
            const int koff = so ^ ((row & 7) << 4);
            const float* s = xf32 + (size_t)(b0 + row) * 64 + (koff >> 1);
            const float4 v0 = *(const float4*)s;
            const float4 v1 = *(const float4*)(s + 4);
            bf16x8 pk;
            pk[0] = (__bf16)v0.x; pk[1] = (__bf16)v0.y;
            pk[2] = (__bf16)v0.z; pk[3] = (__bf16)v0.w;
            pk[4] = (__bf16)v1.x; pk[5] = (__bf16)v1.y;
            pk[6] = (__bf16)v1.z; pk[7] = (__bf16)v1.w;
            *(bf16x8*)(smem + 32768 + slot * 16) = pk;
        }
    } else {
        // single region: [64 rows][1024 B] (64KB): 0..511 hbelow, rest hself
#pragma unroll
        for (int i = 0; i < 16; ++i) {
            const int slot = i * 256 + tid;        // 4096 slots
            const int row = slot >> 6;
            const int so = (slot & 63) * 16;
            const int koff = so ^ ((row & 7) << 4);
            const char* src = (koff < 512)
                ? (const char*)hbelow + (size_t)(b0 + row) * 512 + koff
                : (const char*)hself + (size_t)(b0 + row) * 512 + (koff - 512);
            gload_lds16(src, smem + slot * 16);
        }
    }
    __syncthreads();

    // ---- barrier-free K loop ----
    f32x4 acc[4][2];
#pragma unroll
    for (int mf = 0; mf < 4; ++mf)
#pragma unroll
        for (int nf = 0; nf < 2; ++nf) acc[mf][nf] = f32x4{0.f, 0.f, 0.f, 0.f};

    const int qoff = q * 16;
    const int swzl = (l15 & 7) << 4;
#pragma unroll
    for (int ch = 0; ch < NCH; ++ch) {
        bf16x8 af[4];
#pragma unroll
        for (int mf = 0; mf < 4; ++mf) {
            const int row = mf * 16 + l15;
            const char* ap;
            if (IS_L0) {
                if (ch < 2)
                    ap = smem + 32768 + row * 128 + ((ch * 64 + qoff) ^ swzl);
                else
                    ap = smem + row * 512 + (((ch - 2) * 64 + qoff) ^ swzl);
            } else {
                ap = smem + row * 1024 + ((ch * 64 + qoff) ^ swzl);
            }
            af[mf] = *(const bf16x8*)ap;
        }
#pragma unroll
        for (int mf = 0; mf < 4; ++mf)
#pragma unroll
            for (int nf = 0; nf < 2; ++nf)
                acc[mf][nf] = __builtin_amdgcn_mfma_f32_16x16x32_bf16(
                    af[mf], Breg[ch][nf], acc[mf][nf], 0, 0, 0);
    }

    // ---- pointwise epilogue: gates via 2 shfl_xor(1); wt_store outputs ----
#pragma unroll
    for (int mf = 0; mf < 4; ++mf) {
#pragma unroll
        for (int r = 0; r < 4; ++r) {
            const float a0 = acc[mf][0][r] + b0a;
            const float a1 = acc[mf][1][r] + b1a;
            const float p0 = __shfl_xor(a0, 1);
            const float p1 = __shfl_xor(a1, 1);
            const float gi = gpar ? p0 : a0;
            const float gf = gpar ? a0 : p0;
            const float gg = gpar ? p1 : a1;
            const float go = gpar ? a1 : p1;
            const float cn = fast_sigmoid(gf) * cp[mf][r]
                           + fast_sigmoid(gi) * fast_tanh(gg);
            const float hv = fast_sigmoid(go) * fast_tanh(cn);
            const int rowo = b0 + mf * 16 + q * 4 + r;
            const size_t oidx = (size_t)rowo * 256 + hcol;
            const u16 hb = __builtin_bit_cast(u16, (__bf16)hv);
            const int pr = __shfl_xor((int)(u32)hb, 2);
            const u32 pk = ((u32)hb & 0xffffu) | (((u32)pr) << 16);
            if (gpar) {
                wt_store((u32*)&cst[oidx], __builtin_bit_cast(u32, cn));
            } else if (latout) {
                wt_store((u32*)&latout[oidx], __builtin_bit_cast(u32, hv));
            } else if ((l15 & 3) == 0) {
                wt_store((u32*)hout + ((size_t)rowo * 128 + (hcol >> 1)), pk);
            }
        }
    }
}

// Slot s: blocks 0..255 -> layer0 step s; 256..511 -> layer1 step s-1.
// 256 thr, 64KB LDS -> 2 blocks/CU; (256,2) caps VGPR at 256 (fits Breg+acc).
__global__ __launch_bounds__(256, 2) void lstm_slot(
    const float* __restrict__ xt,
    const u16* __restrict__ h0c, u16* __restrict__ h0n, float* __restrict__ c0,
    const u16* __restrict__ Wp0,
    const float* __restrict__ bih0, const float* __restrict__ bhh0,
    const u16* __restrict__ h1c, u16* __restrict__ h1n, float* __restrict__ c1,
    const u16* __restrict__ Wp1,
    const float* __restrict__ bih1, const float* __restrict__ bhh1,
    float* __restrict__ latout, int do0, int do1)
{
    extern __shared__ char smem[];
    const int tid = threadIdx.x;
    if (blockIdx.x < 256) {
        if (do0)
            run_layer64<LSTM_HIN>(xt, nullptr, h0c, Wp0, bih0, bhh0,
                                  h0n, nullptr, c0, blockIdx.x, smem, tid);
    } else {
        if (do1)
            run_layer64<LSTM_H>(nullptr, h0c, h1c, Wp1, bih1, bhh1,
                                h1n, latout, c1, blockIdx.x - 256, smem, tid);
    }
}

// ---------------------------------------------------------------------------
// K-means tail (round-15 proven): 64 blocks x 256 thr, 32 rows = 4 waves x 8.
// ---------------------------------------------------------------------------
__global__ __launch_bounds__(256, 1) void assign_fused(
    const float* __restrict__ lat, const float* __restrict__ clusters,
    int* __restrict__ ids, float* __restrict__ partial, int* __restrict__ pcount)
{
    extern __shared__ char sm[];
    float* clT    = (float*)sm;                 // [j][k], 64 KB
    float* psum   = (float*)(sm + 65536);       // [k][h], 64 KB
    float* rowbuf = (float*)(sm + 131072);      // [wave][256], 4 KB
    int*   pcnt   = (int*)(sm + 135168);        // [64]

    const int tid = threadIdx.x;
    const int k = tid & 63;
    const int w = tid >> 6;

    for (int i = tid; i < 16384; i += 256) {
        const int kk = i >> 8, j = i & 255;
        clT[j * 64 + kk] = clusters[(size_t)kk * 256 + j];
        psum[i] = 0.f;
    }
    if (tid < 64) pcnt[tid] = 0;
    __syncthreads();

    float* rb = rowbuf + w * 256;
    const int rbase = (int)blockIdx.x * 32 + w * 8;
    for (int rr = 0; rr < 8; ++rr) {
        const int row = rbase + rr;
#pragma unroll
        for (int p = 0; p < 4; ++p)
            rb[p * 64 + k] = lat[(size_t)row * 256 + p * 64 + k];
        float d0 = 0.f, d1 = 0.f, d2 = 0.f, d3 = 0.f;
#pragma unroll 4
        for (int j = 0; j < 256; j += 4) {
            const float t0 = rb[j + 0] - clT[(j + 0) * 64 + k];
            const float t1 = rb[j + 1] - clT[(j + 1) * 64 + k];
            const float t2 = rb[j + 2] - clT[(j + 2) * 64 + k];
            const float t3 = rb[j + 3] - clT[(j + 3) * 64 + k];
            d0 += t0 * t0; d1 += t1 * t1; d2 += t2 * t2; d3 += t3 * t3;
        }
        float d = (d0 + d1) + (d2 + d3);
        int idx = k;
        for (int off = 32; off > 0; off >>= 1) {
            const float od = __shfl_down(d, off, 64);
            const int   oi = __shfl_down(idx, off, 64);
            if (od < d || (od == d && oi < idx)) { d = od; idx = oi; }
        }
        const int best = __shfl(idx, 0, 64);
        if (k == 0) { ids[row] = best; atomicAdd(&pcnt[best], 1); }
#pragma unroll
        for (int p = 0; p < 4; ++p)
            atomicAdd(&psum[best * 256 + p * 64 + k], rb[p * 64 + k]);
    }
    __syncthreads();
    for (int i = tid; i < 16384; i += 256)
        partial[(size_t)blockIdx.x * 16384 + i] = psum[i];
    if (tid < 64) pcount[(size_t)blockIdx.x * 64 + tid] = pcnt[tid];
}

__global__ __launch_bounds__(256) void centroid_final2(
    const float* __restrict__ partial, const int* __restrict__ pcount,
    const float* __restrict__ clusters, float* __restrict__ upd)
{
    const int k = blockIdx.x;
    const int h = threadIdx.x;
    float s = 0.f;
    int c = 0;
    for (int b = 0; b < ASSIGN_BLOCKS; ++b) {
        s += partial[(size_t)b * 16384 + k * 256 + h];
        c += pcount[(size_t)b * 64 + k];
    }
    upd[(size_t)k * LSTM_H + h] = (c > 0)
        ? s / (float)c
        : clusters[(size_t)k * LSTM_H + h];
}

__global__ __launch_bounds__(256) void loss_kernel(
    const float* __restrict__ lat, const int* __restrict__ ids,
    const float* __restrict__ upd, float* __restrict__ out_loss)
{
    float p = 0.f;
    const int total = LSTM_B * LSTM_H;
    for (int idx = blockIdx.x * blockDim.x + threadIdx.x; idx < total;
         idx += gridDim.x * blockDim.x) {
        const int b = idx >> 8;
        const float d = lat[idx] - upd[(size_t)ids[b] * LSTM_H + (idx & 255)];
        p += d * d;
    }
    for (int off = 32; off > 0; off >>= 1) p += __shfl_down(p, off, 64);
    __shared__ float wsum[4];
    const int lane = threadIdx.x & 63, wid = threadIdx.x >> 6;
    if (lane == 0) wsum[wid] = p;
    __syncthreads();
    if (threadIdx.x == 0)
        atomicAdd(out_loss, HALF_BETA * (wsum[0] + wsum[1] + wsum[2] + wsum[3]));
}

// ---------------------------------------------------------------------------
extern "C" void kernel_launch(void* const* d_in, const int* in_sizes, int n_in,
                              void* d_out, int out_size, void* d_ws, size_t ws_size,
                              hipStream_t stream)
{
    const float* X     = (const float*)d_in[0];
    const float* Wih0  = (const float*)d_in[1];
    const float* Whh0  = (const float*)d_in[2];
    const float* bih0  = (const float*)d_in[3];
    const float* bhh0  = (const float*)d_in[4];
    const float* Wih1  = (const float*)d_in[5];
    const float* Whh1  = (const float*)d_in[6];
    const float* bih1  = (const float*)d_in[7];
    const float* bhh1  = (const float*)d_in[8];
    const float* clust = (const float*)d_in[9];

    float* out = (float*)d_out;
    char* base = (char*)d_ws;
    const size_t MB = 1u << 20;
    const size_t KB = 1024;

    u16* Wp0      = (u16*)(base + 0 * MB);              // 640 KB
    u16* Wp1      = (u16*)(base + 1 * MB);              // 1 MB
    u16* h0a      = (u16*)(base + 2 * MB);              // 1 MB each
    u16* h0b      = (u16*)(base + 3 * MB);
    u16* h1a      = (u16*)(base + 4 * MB);
    u16* h1b      = (u16*)(base + 5 * MB);
    float* c0     = (float*)(base + 6 * MB);            // 2 MB
    float* c1     = (float*)(base + 8 * MB);            // 2 MB
    // partial ALIASES c0/c1 (4 MB): c-states dead once assign_fused runs.
    float* partial= (float*)(base + 6 * MB);            // 4 MB (64 x 64 KB)
    float* upd    = (float*)(base + 10 * MB);           // 64 KB
    int* pcount   = (int*)(base + 10 * MB + 64 * KB);   // 16 KB
    int* ids      = (int*)(base + 10 * MB + 80 * KB);   // 8 KB

    const size_t BH = (size_t)LSTM_B * LSTM_H;

    hipMemsetAsync(h0a, 0, MB, stream);
    hipMemsetAsync(h1a, 0, MB, stream);
    hipMemsetAsync(c0, 0, 4 * MB, stream);              // c0+c1 contiguous
    hipMemsetAsync(out + BH, 0, sizeof(float), stream);

    pack_frag<LSTM_HIN><<<320, 256, 0, stream>>>(Wih0, Whh0, Wp0);
    pack_frag<LSTM_H>  <<<512, 256, 0, stream>>>(Wih1, Whh1, Wp1);

    hipFuncSetAttribute((const void*)lstm_slot,
                        hipFuncAttributeMaxDynamicSharedMemorySize, LDS_BYTES);
    hipFuncSetAttribute((const void*)assign_fused,
                        hipFuncAttributeMaxDynamicSharedMemorySize, ASSIGN_LDS);

    u16* h0c = h0a; u16* h0n = h0b;
    u16* h1c = h1a; u16* h1n = h1b;
    for (int s = 0; s <= LSTM_L; ++s) {
        const int do0 = (s < LSTM_L) ? 1 : 0;
        const int do1 = (s > 0) ? 1 : 0;
        const float* xt = do0 ? X + (size_t)s * LSTM_B * LSTM_HIN : nullptr;
        float* lat = (s == LSTM_L) ? out : nullptr;
        lstm_slot<<<512, 256, LDS_BYTES, stream>>>(
            xt, h0c, h0n, c0, Wp0, bih0, bhh0,
            h1c, h1n, c1, Wp1, bih1, bhh1, lat, do0, do1);
        if (do0) { u16* t = h0c; h0c = h0n; h0n = t; }
        if (do1) { u16* t = h1c; h1c = h1n; h1n = t; }
    }

    assign_fused<<<ASSIGN_BLOCKS, 256, ASSIGN_LDS, stream>>>(
        out, clust, ids, partial, pcount);
    centroid_final2<<<NCLUST, 256, 0, stream>>>(partial, pcount, clust, upd);
    loss_kernel<<<256, 256, 0, stream>>>(out, ids, upd, out + BH);
}